// Round 1
// baseline (910.025 us; speedup 1.0000x reference)
//
#include <hip/hip_runtime.h>
#include <hip/hip_bf16.h>
#include <cstdint>
#include <cstddef>

#define T_SEQ 4096
#define HID   2048
#define NH    16
#define HD    128
#define QKVN  6144

typedef unsigned short u16;
typedef __bf16 bf16x8 __attribute__((ext_vector_type(8)));
typedef float  f32x4  __attribute__((ext_vector_type(4)));

typedef const __attribute__((address_space(1))) void* gas_ptr;
typedef __attribute__((address_space(3))) void* las_ptr;

__device__ __forceinline__ void async16(const void* g, void* l) {
  __builtin_amdgcn_global_load_lds((gas_ptr)g, (las_ptr)l, 16, 0, 0);
}

__device__ __forceinline__ u16 f2bf(float f) {
  unsigned int u = __float_as_uint(f);
  u += 0x7fffu + ((u >> 16) & 1u);
  return (u16)(u >> 16);
}

// ---------------- elementwise cast f32 -> bf16 ----------------
__global__ void cast_f32_bf16(const float* __restrict__ in, u16* __restrict__ out, int n) {
  int i = (blockIdx.x * blockDim.x + threadIdx.x) * 4;
  if (i >= n) return;
  float4 v = *(const float4*)&in[i];
  uint2 o;
  o.x = (unsigned)f2bf(v.x) | ((unsigned)f2bf(v.y) << 16);
  o.y = (unsigned)f2bf(v.z) | ((unsigned)f2bf(v.w) << 16);
  *(uint2*)&out[i] = o;
}

// ---------------- transpose + cast: f32 [R][C] -> bf16 [C][R] ----------------
__global__ void transpose_cast(const float* __restrict__ in, u16* __restrict__ out,
                               int R, int C) {
  __shared__ float tile[64][65];
  int c0 = blockIdx.x * 64, r0 = blockIdx.y * 64;
  int tid = threadIdx.x;
#pragma unroll
  for (int i = 0; i < 16; ++i) {
    int e = i * 256 + tid;
    int rr = e >> 6, cc = e & 63;
    tile[rr][cc] = in[(size_t)(r0 + rr) * C + c0 + cc];
  }
  __syncthreads();
#pragma unroll
  for (int i = 0; i < 16; ++i) {
    int e = i * 256 + tid;
    int oc = e >> 6, orr = e & 63;
    out[(size_t)(c0 + oc) * R + r0 + orr] = f2bf(tile[orr][oc]);
  }
}

// ---------------- GEMM: C[M][N] = A[M][K] * BT[N][K]^T  (bf16 in, f32 out) --------
// 128x128 tile, BK=32, 256 threads = 4 waves (2x2), each wave 64x64 = 4x4 frags
__global__ __launch_bounds__(256)
void gemm_bf16_bt(const u16* __restrict__ A, const u16* __restrict__ BT,
                  float* __restrict__ C, int M, int N, int K) {
  __shared__ u16 As[128 * 32];
  __shared__ u16 Bs[128 * 32];
  int tid = threadIdx.x;
  int row0 = blockIdx.y * 128, col0 = blockIdx.x * 128;
  int wv = tid >> 6, lane = tid & 63, lr = lane & 15, lq = lane >> 4;
  int wm = (wv >> 1) * 64, wn = (wv & 1) * 64;
  f32x4 acc[4][4] = {};

  for (int ks = 0; ks < K; ks += 32) {
    __syncthreads();
    int e0 = tid * 8, e1 = 2048 + tid * 8;
    async16(&A[(size_t)(row0 + (e0 >> 5)) * K + ks + (e0 & 31)], &As[e0]);
    async16(&A[(size_t)(row0 + (e1 >> 5)) * K + ks + (e1 & 31)], &As[e1]);
    async16(&BT[(size_t)(col0 + (e0 >> 5)) * K + ks + (e0 & 31)], &Bs[e0]);
    async16(&BT[(size_t)(col0 + (e1 >> 5)) * K + ks + (e1 & 31)], &Bs[e1]);
    __syncthreads();

    bf16x8 a[4], b[4];
#pragma unroll
    for (int mi = 0; mi < 4; ++mi)
      a[mi] = *(const bf16x8*)&As[(wm + mi * 16 + lr) * 32 + lq * 8];
#pragma unroll
    for (int ni = 0; ni < 4; ++ni)
      b[ni] = *(const bf16x8*)&Bs[(wn + ni * 16 + lr) * 32 + lq * 8];
#pragma unroll
    for (int mi = 0; mi < 4; ++mi)
#pragma unroll
      for (int ni = 0; ni < 4; ++ni)
        acc[mi][ni] = __builtin_amdgcn_mfma_f32_16x16x32_bf16(a[mi], b[ni], acc[mi][ni], 0, 0, 0);
  }

#pragma unroll
  for (int mi = 0; mi < 4; ++mi)
#pragma unroll
    for (int ni = 0; ni < 4; ++ni)
#pragma unroll
      for (int r = 0; r < 4; ++r)
        C[(size_t)(row0 + wm + mi * 16 + lq * 4 + r) * N + col0 + wn + ni * 16 + lr] =
            acc[mi][ni][r];
}

// ---------------- RoPE + head-major reorg for Q,K ----------------
// qkv f32 [T][6144] -> Qh,Kh bf16 [NH][T][HD] (roped)
__global__ void rope_reorg(const float* __restrict__ qkv, const int* __restrict__ pos,
                           u16* __restrict__ Qh, u16* __restrict__ Kh) {
  int idx = blockIdx.x * 256 + threadIdx.x;   // T*NH*64 threads
  if (idx >= T_SEQ * NH * 64) return;
  int d = idx & 63;
  int h = (idx >> 6) & (NH - 1);
  int t = idx >> 10;
  float p = (float)pos[t];
  float inv = 1.0f / powf(10000.0f, (float)d * (1.0f / 64.0f));
  float f = p * inv;
  float s, c;
  sincosf(f, &s, &c);

  size_t ib = (size_t)t * QKVN + h * HD + d;
  float q1 = qkv[ib], q2 = qkv[ib + 64];
  float k1 = qkv[ib + HID], k2 = qkv[ib + HID + 64];
  size_t ob = ((size_t)h * T_SEQ + t) * HD + d;
  Qh[ob]      = f2bf(q1 * c - q2 * s);
  Qh[ob + 64] = f2bf(q2 * c + q1 * s);
  Kh[ob]      = f2bf(k1 * c - k2 * s);
  Kh[ob + 64] = f2bf(k2 * c + k1 * s);
}

// ---------------- V transpose: qkv v-part f32 -> Vt bf16 [NH][HD][T] -------------
__global__ void vtrans(const float* __restrict__ qkv, u16* __restrict__ Vt) {
  __shared__ float tile[64][129];
  int t0 = blockIdx.x * 64;
  int h = blockIdx.y;
  int tid = threadIdx.x;
#pragma unroll
  for (int i = 0; i < 32; ++i) {
    int e = i * 256 + tid;
    int tt = e >> 7, d = e & 127;
    tile[tt][d] = qkv[(size_t)(t0 + tt) * QKVN + 2 * HID + h * HD + d];
  }
  __syncthreads();
#pragma unroll
  for (int i = 0; i < 32; ++i) {
    int e = i * 256 + tid;
    int d = e >> 6, tt = e & 63;
    Vt[((size_t)h * HD + d) * T_SEQ + t0 + tt] = f2bf(tile[tt][d]);
  }
}

// ---------------- causal flash attention, 1 wave / block, 32-row Q tile ----------
// Qh,Kh [NH][T][HD], Vt [NH][HD][T] -> attn bf16 [T][HID]
__global__ __launch_bounds__(64)
void attn_fwd(const u16* __restrict__ Qh, const u16* __restrict__ Kh,
              const u16* __restrict__ Vt, u16* __restrict__ attn) {
  __shared__ u16 Ks[32 * 128];   // [kv][d]
  __shared__ u16 Vs[128 * 32];   // [d][kv]
  __shared__ u16 Ps[32 * 32];    // [q][kv]
  int qt = blockIdx.x, h = blockIdx.y;
  int lane = threadIdx.x, lr = lane & 15, lq = lane >> 4;
  int q0 = qt * 32;
  const float scale = 0.08838834764831845f;

  // Q fragments in registers: A-layout, rows q0+mi*16+lr, k = kd*32+lq*8..+7
  bf16x8 qf[2][4];
#pragma unroll
  for (int mi = 0; mi < 2; ++mi)
#pragma unroll
    for (int kd = 0; kd < 4; ++kd)
      qf[mi][kd] = *(const bf16x8*)
          &Qh[((size_t)h * T_SEQ + q0 + mi * 16 + lr) * HD + kd * 32 + lq * 8];

  f32x4 acc_o[2][8] = {};
  float m_run[2][4], l_run[2][4];
#pragma unroll
  for (int mi = 0; mi < 2; ++mi)
#pragma unroll
    for (int r = 0; r < 4; ++r) { m_run[mi][r] = -1e30f; l_run[mi][r] = 0.0f; }

  for (int j = 0; j <= qt; ++j) {
    __syncthreads();
#pragma unroll
    for (int i = 0; i < 8; ++i) {
      int e = i * 512 + lane * 8;
      // K tile [32][128]
      async16(&Kh[((size_t)h * T_SEQ + j * 32 + (e >> 7)) * HD + (e & 127)], &Ks[e]);
      // V tile [128][32] from Vt
      async16(&Vt[((size_t)h * HD + (e >> 5)) * T_SEQ + j * 32 + (e & 31)], &Vs[e]);
    }
    __syncthreads();

    // S = Q K^T  (32x32)
    f32x4 s_acc[2][2] = {};
#pragma unroll
    for (int kd = 0; kd < 4; ++kd) {
      bf16x8 kf0 = *(const bf16x8*)&Ks[(0 * 16 + lr) * 128 + kd * 32 + lq * 8];
      bf16x8 kf1 = *(const bf16x8*)&Ks[(1 * 16 + lr) * 128 + kd * 32 + lq * 8];
#pragma unroll
      for (int mi = 0; mi < 2; ++mi) {
        s_acc[mi][0] = __builtin_amdgcn_mfma_f32_16x16x32_bf16(qf[mi][kd], kf0, s_acc[mi][0], 0, 0, 0);
        s_acc[mi][1] = __builtin_amdgcn_mfma_f32_16x16x32_bf16(qf[mi][kd], kf1, s_acc[mi][1], 0, 0, 0);
      }
    }

    // online softmax
#pragma unroll
    for (int mi = 0; mi < 2; ++mi) {
      float pm[4];
#pragma unroll
      for (int r = 0; r < 4; ++r) {
        int qrow = q0 + mi * 16 + lq * 4 + r;
        float s0 = s_acc[mi][0][r] * scale;
        float s1 = s_acc[mi][1][r] * scale;
        if (j * 32 + lr > qrow)      s0 = -1e30f;
        if (j * 32 + 16 + lr > qrow) s1 = -1e30f;
        s_acc[mi][0][r] = s0;
        s_acc[mi][1][r] = s1;
        pm[r] = fmaxf(s0, s1);
      }
#pragma unroll
      for (int r = 0; r < 4; ++r) {
        pm[r] = fmaxf(pm[r], __shfl_xor(pm[r], 1));
        pm[r] = fmaxf(pm[r], __shfl_xor(pm[r], 2));
        pm[r] = fmaxf(pm[r], __shfl_xor(pm[r], 4));
        pm[r] = fmaxf(pm[r], __shfl_xor(pm[r], 8));
      }
#pragma unroll
      for (int r = 0; r < 4; ++r) {
        float mnew = fmaxf(m_run[mi][r], pm[r]);
        float sf = expf(m_run[mi][r] - mnew);
        float p0 = expf(s_acc[mi][0][r] - mnew);
        float p1 = expf(s_acc[mi][1][r] - mnew);
        float rs = p0 + p1;
        rs += __shfl_xor(rs, 1);
        rs += __shfl_xor(rs, 2);
        rs += __shfl_xor(rs, 4);
        rs += __shfl_xor(rs, 8);
        l_run[mi][r] = l_run[mi][r] * sf + rs;
        m_run[mi][r] = mnew;
#pragma unroll
        for (int nd = 0; nd < 8; ++nd) acc_o[mi][nd][r] *= sf;
        Ps[(mi * 16 + lq * 4 + r) * 32 + lr]      = f2bf(p0);
        Ps[(mi * 16 + lq * 4 + r) * 32 + 16 + lr] = f2bf(p1);
      }
    }

    // O += P V   (32x128, K=32)
#pragma unroll
    for (int mi = 0; mi < 2; ++mi) {
      bf16x8 pa = *(const bf16x8*)&Ps[(mi * 16 + lr) * 32 + lq * 8];
#pragma unroll
      for (int nd = 0; nd < 8; ++nd) {
        bf16x8 vb = *(const bf16x8*)&Vs[(nd * 16 + lr) * 32 + lq * 8];
        acc_o[mi][nd] = __builtin_amdgcn_mfma_f32_16x16x32_bf16(pa, vb, acc_o[mi][nd], 0, 0, 0);
      }
    }
  }

  // epilogue: divide by l and store bf16 [T][HID]
#pragma unroll
  for (int mi = 0; mi < 2; ++mi)
#pragma unroll
    for (int nd = 0; nd < 8; ++nd)
#pragma unroll
      for (int r = 0; r < 4; ++r) {
        int qrow = q0 + mi * 16 + lq * 4 + r;
        float v = acc_o[mi][nd][r] / l_run[mi][r];
        attn[(size_t)qrow * HID + h * HD + nd * 16 + lr] = f2bf(v);
      }
}

extern "C" void kernel_launch(void* const* d_in, const int* in_sizes, int n_in,
                              void* d_out, int out_size, void* d_ws, size_t ws_size,
                              hipStream_t stream) {
  const float* hidden    = (const float*)d_in[0];
  const int*   positions = (const int*)d_in[1];
  const float* w_qkv     = (const float*)d_in[2];
  const float* w_o       = (const float*)d_in[3];
  float* out = (float*)d_out;

  char* p = (char*)d_ws;
  u16* hs_b   = (u16*)p;  p += (size_t)T_SEQ * HID * 2;
  u16* wqkvT  = (u16*)p;  p += (size_t)QKVN * HID * 2;
  u16* woT    = (u16*)p;  p += (size_t)HID * HID * 2;
  float* qkvf = (float*)p; p += (size_t)T_SEQ * QKVN * 4;
  u16* Qh     = (u16*)p;  p += (size_t)T_SEQ * HID * 2;
  u16* Kh     = (u16*)p;  p += (size_t)T_SEQ * HID * 2;
  u16* Vt     = (u16*)p;  p += (size_t)T_SEQ * HID * 2;
  u16* attn_b = (u16*)p;  p += (size_t)T_SEQ * HID * 2;

  cast_f32_bf16<<<(T_SEQ * HID / 4 + 255) / 256, 256, 0, stream>>>(hidden, hs_b, T_SEQ * HID);
  transpose_cast<<<dim3(QKVN / 64, HID / 64), 256, 0, stream>>>(w_qkv, wqkvT, HID, QKVN);
  transpose_cast<<<dim3(HID / 64, HID / 64), 256, 0, stream>>>(w_o, woT, HID, HID);
  gemm_bf16_bt<<<dim3(QKVN / 128, T_SEQ / 128), 256, 0, stream>>>(hs_b, wqkvT, qkvf,
                                                                  T_SEQ, QKVN, HID);
  rope_reorg<<<(T_SEQ * NH * 64 + 255) / 256, 256, 0, stream>>>(qkvf, positions, Qh, Kh);
  vtrans<<<dim3(T_SEQ / 64, NH), 256, 0, stream>>>(qkvf, Vt);
  attn_fwd<<<dim3(T_SEQ / 32, NH), 64, 0, stream>>>(Qh, Kh, Vt, attn_b);
  gemm_bf16_bt<<<dim3(HID / 128, T_SEQ / 128), 256, 0, stream>>>(attn_b, woT, out,
                                                                 T_SEQ, HID, HID);
}

// Round 2
// 777.119 us; speedup vs baseline: 1.1710x; 1.1710x over previous
//
#include <hip/hip_runtime.h>
#include <hip/hip_bf16.h>
#include <cstdint>
#include <cstddef>

#define T_SEQ 4096
#define HID   2048
#define NH    16
#define HD    128
#define QKVN  6144

typedef unsigned short u16;
typedef __bf16 bf16x8 __attribute__((ext_vector_type(8)));
typedef float  f32x4  __attribute__((ext_vector_type(4)));

typedef const __attribute__((address_space(1))) void* gas_ptr;
typedef __attribute__((address_space(3))) void* las_ptr;

__device__ __forceinline__ void async16(const void* g, void* l) {
  __builtin_amdgcn_global_load_lds((gas_ptr)g, (las_ptr)l, 16, 0, 0);
}

__device__ __forceinline__ u16 f2bf(float f) {
  unsigned int u = __float_as_uint(f);
  u += 0x7fffu + ((u >> 16) & 1u);
  return (u16)(u >> 16);
}

// ---------------- elementwise cast f32 -> bf16 ----------------
__global__ void cast_f32_bf16(const float* __restrict__ in, u16* __restrict__ out, int n) {
  int i = (blockIdx.x * blockDim.x + threadIdx.x) * 4;
  if (i >= n) return;
  float4 v = *(const float4*)&in[i];
  uint2 o;
  o.x = (unsigned)f2bf(v.x) | ((unsigned)f2bf(v.y) << 16);
  o.y = (unsigned)f2bf(v.z) | ((unsigned)f2bf(v.w) << 16);
  *(uint2*)&out[i] = o;
}

// ---------------- transpose + cast: f32 [R][C] -> bf16 [C][R] ----------------
__global__ void transpose_cast(const float* __restrict__ in, u16* __restrict__ out,
                               int R, int C) {
  __shared__ float tile[64][65];
  int c0 = blockIdx.x * 64, r0 = blockIdx.y * 64;
  int tid = threadIdx.x;
#pragma unroll
  for (int i = 0; i < 16; ++i) {
    int e = i * 256 + tid;
    int rr = e >> 6, cc = e & 63;
    tile[rr][cc] = in[(size_t)(r0 + rr) * C + c0 + cc];
  }
  __syncthreads();
#pragma unroll
  for (int i = 0; i < 16; ++i) {
    int e = i * 256 + tid;
    int oc = e >> 6, orr = e & 63;
    out[(size_t)(c0 + oc) * R + r0 + orr] = f2bf(tile[orr][oc]);
  }
}

// ---------------- GEMM: C[M][N] = A[M][K] * BT[N][K]^T  (bf16 in, f32 out) --------
__global__ __launch_bounds__(256)
void gemm_bf16_bt(const u16* __restrict__ A, const u16* __restrict__ BT,
                  float* __restrict__ C, int M, int N, int K) {
  __shared__ u16 As[128 * 32];
  __shared__ u16 Bs[128 * 32];
  int tid = threadIdx.x;
  int row0 = blockIdx.y * 128, col0 = blockIdx.x * 128;
  int wv = tid >> 6, lane = tid & 63, lr = lane & 15, lq = lane >> 4;
  int wm = (wv >> 1) * 64, wn = (wv & 1) * 64;
  f32x4 acc[4][4] = {};

  for (int ks = 0; ks < K; ks += 32) {
    __syncthreads();
    int e0 = tid * 8, e1 = 2048 + tid * 8;
    async16(&A[(size_t)(row0 + (e0 >> 5)) * K + ks + (e0 & 31)], &As[e0]);
    async16(&A[(size_t)(row0 + (e1 >> 5)) * K + ks + (e1 & 31)], &As[e1]);
    async16(&BT[(size_t)(col0 + (e0 >> 5)) * K + ks + (e0 & 31)], &Bs[e0]);
    async16(&BT[(size_t)(col0 + (e1 >> 5)) * K + ks + (e1 & 31)], &Bs[e1]);
    __syncthreads();

    bf16x8 a[4], b[4];
#pragma unroll
    for (int mi = 0; mi < 4; ++mi)
      a[mi] = *(const bf16x8*)&As[(wm + mi * 16 + lr) * 32 + lq * 8];
#pragma unroll
    for (int ni = 0; ni < 4; ++ni)
      b[ni] = *(const bf16x8*)&Bs[(wn + ni * 16 + lr) * 32 + lq * 8];
#pragma unroll
    for (int mi = 0; mi < 4; ++mi)
#pragma unroll
      for (int ni = 0; ni < 4; ++ni)
        acc[mi][ni] = __builtin_amdgcn_mfma_f32_16x16x32_bf16(a[mi], b[ni], acc[mi][ni], 0, 0, 0);
  }

#pragma unroll
  for (int mi = 0; mi < 4; ++mi)
#pragma unroll
    for (int ni = 0; ni < 4; ++ni)
#pragma unroll
      for (int r = 0; r < 4; ++r)
        C[(size_t)(row0 + wm + mi * 16 + lq * 4 + r) * N + col0 + wn + ni * 16 + lr] =
            acc[mi][ni][r];
}

// ---------------- RoPE + head-major reorg for Q,K ----------------
__global__ void rope_reorg(const float* __restrict__ qkv, const int* __restrict__ pos,
                           u16* __restrict__ Qh, u16* __restrict__ Kh) {
  int idx = blockIdx.x * 256 + threadIdx.x;
  if (idx >= T_SEQ * NH * 64) return;
  int d = idx & 63;
  int h = (idx >> 6) & (NH - 1);
  int t = idx >> 10;
  float p = (float)pos[t];
  // 1/theta^(d/64) = 2^(-d * log2(10000)/64)
  float inv = exp2f((float)d * -0.20762050594046932f);
  float f = p * inv;
  float s, c;
  __sincosf(f, &s, &c);

  size_t ib = (size_t)t * QKVN + h * HD + d;
  float q1 = qkv[ib], q2 = qkv[ib + 64];
  float k1 = qkv[ib + HID], k2 = qkv[ib + HID + 64];
  size_t ob = ((size_t)h * T_SEQ + t) * HD + d;
  Qh[ob]      = f2bf(q1 * c - q2 * s);
  Qh[ob + 64] = f2bf(q2 * c + q1 * s);
  Kh[ob]      = f2bf(k1 * c - k2 * s);
  Kh[ob + 64] = f2bf(k2 * c + k1 * s);
}

// ---------------- V transpose: qkv v-part f32 -> Vt bf16 [NH][HD][T] -------------
__global__ void vtrans(const float* __restrict__ qkv, u16* __restrict__ Vt) {
  __shared__ float tile[64][129];
  int t0 = blockIdx.x * 64;
  int h = blockIdx.y;
  int tid = threadIdx.x;
#pragma unroll
  for (int i = 0; i < 32; ++i) {
    int e = i * 256 + tid;
    int tt = e >> 7, d = e & 127;
    tile[tt][d] = qkv[(size_t)(t0 + tt) * QKVN + 2 * HID + h * HD + d];
  }
  __syncthreads();
#pragma unroll
  for (int i = 0; i < 32; ++i) {
    int e = i * 256 + tid;
    int d = e >> 6, tt = e & 63;
    Vt[((size_t)h * HD + d) * T_SEQ + t0 + tt] = f2bf(tile[tt][d]);
  }
}

// ---------------- causal flash attention v2 -------------------------------------
// 4 waves/block, Q-tile 128 (32 rows/wave), KV tile 64.
// K,V,P LDS tiles XOR-swizzled (T2): global_load_lds dest linear, source
// pre-permuted with chunk ^= (row&7); reads apply byte ^= (row&7)<<4.
#define SCL2 0.12753224f  /* (1/sqrt(128)) * log2(e) */

__global__ __launch_bounds__(256)
void attn_fwd(const u16* __restrict__ Qh, const u16* __restrict__ Kh,
              const u16* __restrict__ Vt, u16* __restrict__ attn) {
  __shared__ u16 Ks[64 * 128];        // [kv][d], 256B rows, swizzled
  __shared__ u16 Vs[128 * 64];        // [d][kv], 128B rows, swizzled
  __shared__ u16 Ps[4][32 * 64];      // per-wave [q][kv], 128B rows, swizzled
  const char* KsB = (const char*)Ks;
  const char* VsB = (const char*)Vs;

  int tid = threadIdx.x;
  int wv = tid >> 6, lane = tid & 63, lr = lane & 15, lq = lane >> 4;
  int bq = blockIdx.x, h = blockIdx.y;
  int q0 = bq * 128;
  int wrow0 = q0 + wv * 32;
  char* PsB = (char*)&Ps[wv][0];

  // Q fragments: rows wrow0 + mi*16 + lr, k = kd*32 + lq*8
  bf16x8 qf[2][4];
#pragma unroll
  for (int mi = 0; mi < 2; ++mi)
#pragma unroll
    for (int kd = 0; kd < 4; ++kd)
      qf[mi][kd] = *(const bf16x8*)
          &Qh[((size_t)h * T_SEQ + wrow0 + mi * 16 + lr) * HD + kd * 32 + lq * 8];

  f32x4 acc_o[2][8] = {};
  float m_run[2][4], l_run[2][4];
#pragma unroll
  for (int mi = 0; mi < 2; ++mi)
#pragma unroll
    for (int r = 0; r < 4; ++r) { m_run[mi][r] = -1e30f; l_run[mi][r] = 0.0f; }

  int nt = (q0 >> 6) + 2;   // KV tiles covering [0, q0+128)
  for (int j = 0; j < nt; ++j) {
    int jb = j * 64;
    __syncthreads();
    // stage K tile [64][128]: 1024 16B chunks, 16 chunks/row; source pre-swizzled
#pragma unroll
    for (int k = 0; k < 4; ++k) {
      int c = k * 256 + tid;
      int row = c >> 4;
      int sc = (c ^ (row & 7)) & 15;
      async16(&Kh[((size_t)h * T_SEQ + jb + row) * HD + sc * 8], &Ks[c * 8]);
    }
    // stage V tile [128][64]: 1024 chunks, 8 chunks/row
#pragma unroll
    for (int k = 0; k < 4; ++k) {
      int c = k * 256 + tid;
      int row = c >> 3;
      int sc = (c ^ (row & 7)) & 7;
      async16(&Vt[((size_t)h * HD + row) * T_SEQ + jb + sc * 8], &Vs[c * 8]);
    }
    __syncthreads();

    if (jb <= wrow0 + 31) {           // wave-uniform: this wave has live rows
      // ---- S = Q K^T  (32 x 64) ----
      f32x4 s_acc[2][4] = {};
#pragma unroll
      for (int kd = 0; kd < 4; ++kd) {
#pragma unroll
        for (int nj = 0; nj < 4; ++nj) {
          int row = nj * 16 + lr;
          int byt = (row << 8) + kd * 64 + lq * 16;
          bf16x8 kf = *(const bf16x8*)(KsB + (byt ^ ((row & 7) << 4)));
#pragma unroll
          for (int mi = 0; mi < 2; ++mi)
            s_acc[mi][nj] = __builtin_amdgcn_mfma_f32_16x16x32_bf16(
                qf[mi][kd], kf, s_acc[mi][nj], 0, 0, 0);
        }
      }

      bool diag = (jb + 63 > wrow0);  // wave-uniform: tile touches causal edge
      // ---- online softmax ----
#pragma unroll
      for (int mi = 0; mi < 2; ++mi) {
        float pm[4];
#pragma unroll
        for (int r = 0; r < 4; ++r) {
          int qrow = wrow0 + mi * 16 + lq * 4 + r;
          float mx = -1e30f;
#pragma unroll
          for (int nj = 0; nj < 4; ++nj) {
            float s = s_acc[mi][nj][r] * SCL2;
            if (diag && (jb + nj * 16 + lr > qrow)) s = -1e30f;
            s_acc[mi][nj][r] = s;
            mx = fmaxf(mx, s);
          }
          pm[r] = mx;
        }
#pragma unroll
        for (int r = 0; r < 4; ++r) {
          pm[r] = fmaxf(pm[r], __shfl_xor(pm[r], 1));
          pm[r] = fmaxf(pm[r], __shfl_xor(pm[r], 2));
          pm[r] = fmaxf(pm[r], __shfl_xor(pm[r], 4));
          pm[r] = fmaxf(pm[r], __shfl_xor(pm[r], 8));
        }
#pragma unroll
        for (int r = 0; r < 4; ++r) {
          float mnew = fmaxf(m_run[mi][r], pm[r]);
          float sf = exp2f(m_run[mi][r] - mnew);
          m_run[mi][r] = mnew;
          int prow = mi * 16 + lq * 4 + r;
          float rs = 0.0f;
#pragma unroll
          for (int nj = 0; nj < 4; ++nj) {
            float p = exp2f(s_acc[mi][nj][r] - mnew);
            rs += p;
            int byt = (prow << 7) + (nj * 16 + lr) * 2;
            *(u16*)(PsB + (byt ^ ((prow & 7) << 4))) = f2bf(p);
          }
          rs += __shfl_xor(rs, 1);
          rs += __shfl_xor(rs, 2);
          rs += __shfl_xor(rs, 4);
          rs += __shfl_xor(rs, 8);
          l_run[mi][r] = l_run[mi][r] * sf + rs;
#pragma unroll
          for (int nd = 0; nd < 8; ++nd) acc_o[mi][nd][r] *= sf;
        }
      }

      // ---- O += P V  (32 x 128, K=64) ----
#pragma unroll
      for (int kq = 0; kq < 2; ++kq) {
#pragma unroll
        for (int mi = 0; mi < 2; ++mi) {
          int prow = mi * 16 + lr;
          int pbyt = (prow << 7) + kq * 64 + lq * 16;
          bf16x8 pa = *(const bf16x8*)(PsB + (pbyt ^ ((prow & 7) << 4)));
#pragma unroll
          for (int nd = 0; nd < 8; ++nd) {
            int vrow = nd * 16 + lr;
            int vbyt = (vrow << 7) + kq * 64 + lq * 16;
            bf16x8 vb = *(const bf16x8*)(VsB + (vbyt ^ ((vrow & 7) << 4)));
            acc_o[mi][nd] = __builtin_amdgcn_mfma_f32_16x16x32_bf16(
                pa, vb, acc_o[mi][nd], 0, 0, 0);
          }
        }
      }
    }
  }

  // epilogue
#pragma unroll
  for (int mi = 0; mi < 2; ++mi)
#pragma unroll
    for (int nd = 0; nd < 8; ++nd)
#pragma unroll
      for (int r = 0; r < 4; ++r) {
        int qrow = wrow0 + mi * 16 + lq * 4 + r;
        float v = acc_o[mi][nd][r] / l_run[mi][r];
        attn[(size_t)qrow * HID + h * HD + nd * 16 + lr] = f2bf(v);
      }
}

extern "C" void kernel_launch(void* const* d_in, const int* in_sizes, int n_in,
                              void* d_out, int out_size, void* d_ws, size_t ws_size,
                              hipStream_t stream) {
  const float* hidden    = (const float*)d_in[0];
  const int*   positions = (const int*)d_in[1];
  const float* w_qkv     = (const float*)d_in[2];
  const float* w_o       = (const float*)d_in[3];
  float* out = (float*)d_out;

  char* p = (char*)d_ws;
  u16* hs_b   = (u16*)p;  p += (size_t)T_SEQ * HID * 2;
  u16* wqkvT  = (u16*)p;  p += (size_t)QKVN * HID * 2;
  u16* woT    = (u16*)p;  p += (size_t)HID * HID * 2;
  float* qkvf = (float*)p; p += (size_t)T_SEQ * QKVN * 4;
  u16* Qh     = (u16*)p;  p += (size_t)T_SEQ * HID * 2;
  u16* Kh     = (u16*)p;  p += (size_t)T_SEQ * HID * 2;
  u16* Vt     = (u16*)p;  p += (size_t)T_SEQ * HID * 2;
  u16* attn_b = (u16*)p;  p += (size_t)T_SEQ * HID * 2;

  cast_f32_bf16<<<(T_SEQ * HID / 4 + 255) / 256, 256, 0, stream>>>(hidden, hs_b, T_SEQ * HID);
  transpose_cast<<<dim3(QKVN / 64, HID / 64), 256, 0, stream>>>(w_qkv, wqkvT, HID, QKVN);
  transpose_cast<<<dim3(HID / 64, HID / 64), 256, 0, stream>>>(w_o, woT, HID, HID);
  gemm_bf16_bt<<<dim3(QKVN / 128, T_SEQ / 128), 256, 0, stream>>>(hs_b, wqkvT, qkvf,
                                                                  T_SEQ, QKVN, HID);
  rope_reorg<<<(T_SEQ * NH * 64 + 255) / 256, 256, 0, stream>>>(qkvf, positions, Qh, Kh);
  vtrans<<<dim3(T_SEQ / 64, NH), 256, 0, stream>>>(qkvf, Vt);
  attn_fwd<<<dim3(T_SEQ / 128, NH), 256, 0, stream>>>(Qh, Kh, Vt, attn_b);
  gemm_bf16_bt<<<dim3(HID / 128, T_SEQ / 128), 256, 0, stream>>>(attn_b, woT, out,
                                                                 T_SEQ, HID, HID);
}

// Round 4
// 559.589 us; speedup vs baseline: 1.6262x; 1.3887x over previous
//
#include <hip/hip_runtime.h>
#include <hip/hip_bf16.h>
#include <cstdint>
#include <cstddef>

#define T_SEQ 4096
#define HID   2048
#define NH    16
#define HD    128
#define QKVN  6144
#define KVB   32

typedef unsigned short u16;
typedef __bf16 bf16x8 __attribute__((ext_vector_type(8)));
typedef float  f32x4  __attribute__((ext_vector_type(4)));

typedef const __attribute__((address_space(1))) void* gas_ptr;
typedef __attribute__((address_space(3))) void* las_ptr;

__device__ __forceinline__ void async16(const void* g, void* l) {
  __builtin_amdgcn_global_load_lds((gas_ptr)g, (las_ptr)l, 16, 0, 0);
}

__device__ __forceinline__ u16 f2bf(float f) {
  unsigned int u = __float_as_uint(f);
  u += 0x7fffu + ((u >> 16) & 1u);
  return (u16)(u >> 16);
}

// ---------------- elementwise cast f32 -> bf16 ----------------
__global__ void cast_f32_bf16(const float* __restrict__ in, u16* __restrict__ out, int n) {
  int i = (blockIdx.x * blockDim.x + threadIdx.x) * 4;
  if (i >= n) return;
  float4 v = *(const float4*)&in[i];
  uint2 o;
  o.x = (unsigned)f2bf(v.x) | ((unsigned)f2bf(v.y) << 16);
  o.y = (unsigned)f2bf(v.z) | ((unsigned)f2bf(v.w) << 16);
  *(uint2*)&out[i] = o;
}

// ---------------- transpose + cast: f32 [R][C] -> bf16 [C][R] ----------------
__global__ void transpose_cast(const float* __restrict__ in, u16* __restrict__ out,
                               int R, int C) {
  __shared__ float tile[64][65];
  int c0 = blockIdx.x * 64, r0 = blockIdx.y * 64;
  int tid = threadIdx.x;
#pragma unroll
  for (int i = 0; i < 16; ++i) {
    int e = i * 256 + tid;
    int rr = e >> 6, cc = e & 63;
    tile[rr][cc] = in[(size_t)(r0 + rr) * C + c0 + cc];
  }
  __syncthreads();
#pragma unroll
  for (int i = 0; i < 16; ++i) {
    int e = i * 256 + tid;
    int oc = e >> 6, orr = e & 63;
    out[(size_t)(c0 + oc) * R + r0 + orr] = f2bf(tile[orr][oc]);
  }
}

// ---------------- GEMM: C[M][N] = A[M][K] * BT[N][K]^T  (bf16 in, f32 out) --------
// 128x128 tile, BK=32, double-buffered staging.
__global__ __launch_bounds__(256)
void gemm_bf16_bt(const u16* __restrict__ A, const u16* __restrict__ BT,
                  float* __restrict__ C, int M, int N, int K) {
  __shared__ u16 As[2][128 * 32];
  __shared__ u16 Bs[2][128 * 32];
  int tid = threadIdx.x;
  int row0 = blockIdx.y * 128, col0 = blockIdx.x * 128;
  int wv = tid >> 6, lane = tid & 63, lr = lane & 15, lq = lane >> 4;
  int wm = (wv >> 1) * 64, wn = (wv & 1) * 64;
  f32x4 acc[4][4] = {};

  auto stage = [&](int buf, int ks) {
#pragma unroll
    for (int k = 0; k < 2; ++k) {
      int c = k * 256 + tid;            // 512 chunks per matrix, dest lane-linear
      int row = c >> 2, col = c & 3;
      async16(&A[(size_t)(row0 + row) * K + ks + col * 8], &As[buf][c * 8]);
      async16(&BT[(size_t)(col0 + row) * K + ks + col * 8], &Bs[buf][c * 8]);
    }
  };

  stage(0, 0);
  __syncthreads();
  int nk = K >> 5;
  for (int t = 0; t < nk; ++t) {
    int cur = t & 1;
    if (t + 1 < nk) stage(cur ^ 1, (t + 1) * 32);

    bf16x8 a[4], b[4];
#pragma unroll
    for (int mi = 0; mi < 4; ++mi)
      a[mi] = *(const bf16x8*)&As[cur][(wm + mi * 16 + lr) * 32 + lq * 8];
#pragma unroll
    for (int ni = 0; ni < 4; ++ni)
      b[ni] = *(const bf16x8*)&Bs[cur][(wn + ni * 16 + lr) * 32 + lq * 8];
#pragma unroll
    for (int mi = 0; mi < 4; ++mi)
#pragma unroll
      for (int ni = 0; ni < 4; ++ni)
        acc[mi][ni] = __builtin_amdgcn_mfma_f32_16x16x32_bf16(a[mi], b[ni], acc[mi][ni], 0, 0, 0);
    __syncthreads();
  }

#pragma unroll
  for (int mi = 0; mi < 4; ++mi)
#pragma unroll
    for (int ni = 0; ni < 4; ++ni)
#pragma unroll
      for (int r = 0; r < 4; ++r)
        C[(size_t)(row0 + wm + mi * 16 + lq * 4 + r) * N + col0 + wn + ni * 16 + lr] =
            acc[mi][ni][r];
}

// ---------------- RoPE + head-major reorg for Q,K ----------------
__global__ void rope_reorg(const float* __restrict__ qkv, const int* __restrict__ pos,
                           u16* __restrict__ Qh, u16* __restrict__ Kh) {
  int idx = blockIdx.x * 256 + threadIdx.x;
  if (idx >= T_SEQ * NH * 64) return;
  int d = idx & 63;
  int h = (idx >> 6) & (NH - 1);
  int t = idx >> 10;
  float p = (float)pos[t];
  float inv = exp2f((float)d * -0.20762050594046932f);
  float f = p * inv;
  float s, c;
  __sincosf(f, &s, &c);

  size_t ib = (size_t)t * QKVN + h * HD + d;
  float q1 = qkv[ib], q2 = qkv[ib + 64];
  float k1 = qkv[ib + HID], k2 = qkv[ib + HID + 64];
  size_t ob = ((size_t)h * T_SEQ + t) * HD + d;
  Qh[ob]      = f2bf(q1 * c - q2 * s);
  Qh[ob + 64] = f2bf(q2 * c + q1 * s);
  Kh[ob]      = f2bf(k1 * c - k2 * s);
  Kh[ob + 64] = f2bf(k2 * c + k1 * s);
}

// ---------------- V transpose: qkv v-part f32 -> Vt bf16 [NH][HD][T] -------------
__global__ void vtrans(const float* __restrict__ qkv, u16* __restrict__ Vt) {
  __shared__ float tile[64][129];
  int t0 = blockIdx.x * 64;
  int h = blockIdx.y;
  int tid = threadIdx.x;
#pragma unroll
  for (int i = 0; i < 32; ++i) {
    int e = i * 256 + tid;
    int tt = e >> 7, d = e & 127;
    tile[tt][d] = qkv[(size_t)(t0 + tt) * QKVN + 2 * HID + h * HD + d];
  }
  __syncthreads();
#pragma unroll
  for (int i = 0; i < 32; ++i) {
    int e = i * 256 + tid;
    int d = e >> 6, tt = e & 63;
    Vt[((size_t)h * HD + d) * T_SEQ + t0 + tt] = f2bf(tile[tt][d]);
  }
}

// ---------------- causal flash attention v4 -------------------------------------
// 4 waves/block, Q-tile 128 (32 rows/wave), KVBLK=32, double-buffered staging,
// work-balanced block decode. K XOR-swizzled (256B rows); V/P linear (64B rows,
// inherently conflict-free; dest must be lane-linear for global_load_lds).
#define SCL2 0.12753224f  /* (1/sqrt(128)) * log2(e) */

__global__ __launch_bounds__(256)
void attn_fwd(const u16* __restrict__ Qh, const u16* __restrict__ Kh,
              const u16* __restrict__ Vt, u16* __restrict__ attn) {
  __shared__ u16 Ks[2][32 * 128];   // [kv][d] 256B rows, XOR-8 swizzle, 8KB each
  __shared__ u16 Vs[2][128 * 32];   // [d][kv] 64B rows, linear, 8KB each
  __shared__ u16 Ps[4][32 * 32];    // per-wave [q][kv] 64B rows, linear

  int tid = threadIdx.x;
  int wv = tid >> 6, lane = tid & 63, lr = lane & 15, lq = lane >> 4;
  // balanced decode: CU-paired blocks get bq and 31-bq
  int id = blockIdx.x;
  int h = id >> 5;
  int bq = (id < 256) ? (id & 31) : 31 - (id & 31);
  int q0 = bq * 128, wrow0 = q0 + wv * 32;

  // Q fragments: rows wrow0 + mi*16 + lr, k = kd*32 + lq*8
  bf16x8 qf[2][4];
#pragma unroll
  for (int mi = 0; mi < 2; ++mi)
#pragma unroll
    for (int kd = 0; kd < 4; ++kd)
      qf[mi][kd] = *(const bf16x8*)
          &Qh[((size_t)h * T_SEQ + wrow0 + mi * 16 + lr) * HD + kd * 32 + lq * 8];

  f32x4 acc_o[2][8] = {};
  float m_run[2][4], l_run[2][4];
#pragma unroll
  for (int mi = 0; mi < 2; ++mi)
#pragma unroll
    for (int r = 0; r < 4; ++r) { m_run[mi][r] = -1e30f; l_run[mi][r] = 0.0f; }

  auto stage = [&](int buf, int jb) {
#pragma unroll
    for (int k = 0; k < 2; ++k) {      // K tile: 512 chunks, 16/row, src pre-swz
      int c = k * 256 + tid;
      int row = c >> 4;
      int sc = (c ^ (row & 7)) & 15;
      async16(&Kh[((size_t)h * T_SEQ + jb + row) * HD + sc * 8], &Ks[buf][c * 8]);
    }
#pragma unroll
    for (int k = 0; k < 2; ++k) {      // V tile: 512 chunks, 4/row, linear
      int c = k * 256 + tid;
      int row = c >> 2, col = c & 3;
      async16(&Vt[((size_t)h * HD + row) * T_SEQ + jb + col * 8], &Vs[buf][c * 8]);
    }
  };

  int nt = bq * 4 + 4;
  stage(0, 0);
  __syncthreads();

  for (int j = 0; j < nt; ++j) {
    int cur = j & 1;
    int jb = j * KVB;
    if (j + 1 < nt) stage(cur ^ 1, jb + KVB);

    if (jb <= wrow0 + 31) {
      const char* KsB = (const char*)&Ks[cur][0];

      // ---- S = Q K^T  (32 x 32) ----
      f32x4 s_acc[2][2] = {};
#pragma unroll
      for (int kd = 0; kd < 4; ++kd) {
#pragma unroll
        for (int nj = 0; nj < 2; ++nj) {
          int row = nj * 16 + lr;
          int byt = (row << 8) + kd * 64 + lq * 16;
          bf16x8 kf = *(const bf16x8*)(KsB + (byt ^ ((row & 7) << 4)));
#pragma unroll
          for (int mi = 0; mi < 2; ++mi)
            s_acc[mi][nj] = __builtin_amdgcn_mfma_f32_16x16x32_bf16(
                qf[mi][kd], kf, s_acc[mi][nj], 0, 0, 0);
        }
      }

      bool diag = (jb + KVB - 1 > wrow0);
      // ---- online softmax ----
#pragma unroll
      for (int mi = 0; mi < 2; ++mi) {
        float pm[4];
#pragma unroll
        for (int r = 0; r < 4; ++r) {
          int qrow = wrow0 + mi * 16 + lq * 4 + r;
          float mx = -1e30f;
#pragma unroll
          for (int nj = 0; nj < 2; ++nj) {
            float s = s_acc[mi][nj][r] * SCL2;
            if (diag && (jb + nj * 16 + lr > qrow)) s = -1e30f;
            s_acc[mi][nj][r] = s;
            mx = fmaxf(mx, s);
          }
          pm[r] = mx;
        }
#pragma unroll
        for (int r = 0; r < 4; ++r) {
          pm[r] = fmaxf(pm[r], __shfl_xor(pm[r], 1));
          pm[r] = fmaxf(pm[r], __shfl_xor(pm[r], 2));
          pm[r] = fmaxf(pm[r], __shfl_xor(pm[r], 4));
          pm[r] = fmaxf(pm[r], __shfl_xor(pm[r], 8));
        }
#pragma unroll
        for (int r = 0; r < 4; ++r) {
          float mnew = fmaxf(m_run[mi][r], pm[r]);
          float sf = exp2f(m_run[mi][r] - mnew);
          m_run[mi][r] = mnew;
          int prow = mi * 16 + lq * 4 + r;
          float rs = 0.0f;
#pragma unroll
          for (int nj = 0; nj < 2; ++nj) {
            float p = exp2f(s_acc[mi][nj][r] - mnew);
            rs += p;
            Ps[wv][prow * 32 + nj * 16 + lr] = f2bf(p);
          }
          rs += __shfl_xor(rs, 1);
          rs += __shfl_xor(rs, 2);
          rs += __shfl_xor(rs, 4);
          rs += __shfl_xor(rs, 8);
          l_run[mi][r] = l_run[mi][r] * sf + rs;
#pragma unroll
          for (int nd = 0; nd < 8; ++nd) acc_o[mi][nd][r] *= sf;
        }
      }

      // ---- O += P V  (32 x 128, K=32) ----
#pragma unroll
      for (int mi = 0; mi < 2; ++mi) {
        bf16x8 pa = *(const bf16x8*)&Ps[wv][(mi * 16 + lr) * 32 + lq * 8];
#pragma unroll
        for (int nd = 0; nd < 8; ++nd) {
          bf16x8 vb = *(const bf16x8*)&Vs[cur][(nd * 16 + lr) * 32 + lq * 8];
          acc_o[mi][nd] = __builtin_amdgcn_mfma_f32_16x16x32_bf16(
              pa, vb, acc_o[mi][nd], 0, 0, 0);
        }
      }
    }
    __syncthreads();
  }

  // epilogue
#pragma unroll
  for (int mi = 0; mi < 2; ++mi)
#pragma unroll
    for (int r = 0; r < 4; ++r) {
      float rl = 1.0f / l_run[mi][r];
      int qrow = wrow0 + mi * 16 + lq * 4 + r;
#pragma unroll
      for (int nd = 0; nd < 8; ++nd)
        attn[(size_t)qrow * HID + h * HD + nd * 16 + lr] = f2bf(acc_o[mi][nd][r] * rl);
    }
}

extern "C" void kernel_launch(void* const* d_in, const int* in_sizes, int n_in,
                              void* d_out, int out_size, void* d_ws, size_t ws_size,
                              hipStream_t stream) {
  const float* hidden    = (const float*)d_in[0];
  const int*   positions = (const int*)d_in[1];
  const float* w_qkv     = (const float*)d_in[2];
  const float* w_o       = (const float*)d_in[3];
  float* out = (float*)d_out;

  char* p = (char*)d_ws;
  u16* hs_b   = (u16*)p;  p += (size_t)T_SEQ * HID * 2;
  u16* wqkvT  = (u16*)p;  p += (size_t)QKVN * HID * 2;
  u16* woT    = (u16*)p;  p += (size_t)HID * HID * 2;
  float* qkvf = (float*)p; p += (size_t)T_SEQ * QKVN * 4;
  u16* Qh     = (u16*)p;  p += (size_t)T_SEQ * HID * 2;
  u16* Kh     = (u16*)p;  p += (size_t)T_SEQ * HID * 2;
  u16* Vt     = (u16*)p;  p += (size_t)T_SEQ * HID * 2;
  u16* attn_b = (u16*)p;  p += (size_t)T_SEQ * HID * 2;

  cast_f32_bf16<<<(T_SEQ * HID / 4 + 255) / 256, 256, 0, stream>>>(hidden, hs_b, T_SEQ * HID);
  transpose_cast<<<dim3(QKVN / 64, HID / 64), 256, 0, stream>>>(w_qkv, wqkvT, HID, QKVN);
  transpose_cast<<<dim3(HID / 64, HID / 64), 256, 0, stream>>>(w_o, woT, HID, HID);
  gemm_bf16_bt<<<dim3(QKVN / 128, T_SEQ / 128), 256, 0, stream>>>(hs_b, wqkvT, qkvf,
                                                                  T_SEQ, QKVN, HID);
  rope_reorg<<<(T_SEQ * NH * 64 + 255) / 256, 256, 0, stream>>>(qkvf, positions, Qh, Kh);
  vtrans<<<dim3(T_SEQ / 64, NH), 256, 0, stream>>>(qkvf, Vt);
  attn_fwd<<<512, 256, 0, stream>>>(Qh, Kh, Vt, attn_b);
  gemm_bf16_bt<<<dim3(HID / 128, T_SEQ / 128), 256, 0, stream>>>(attn_b, woT, out,
                                                                 T_SEQ, HID, HID);
}